// Round 3
// baseline (104.874 us; speedup 1.0000x reference)
//
#include <hip/hip_runtime.h>
#include <hip/hip_bf16.h>

typedef __attribute__((ext_vector_type(8))) short bf16x8;
typedef __attribute__((ext_vector_type(4))) float f32x4;
typedef unsigned short u16;

static constexpr int KDIM = 784;   // 28*28
static constexpr int KP   = 800;   // K padded (weff zero-pads k>=784)
static constexpr int NDIM = 300;
static constexpr int NP   = 320;
static constexpr int DDIM = 10;
static constexpr int BM   = 128;   // rows per block
static constexpr int BK   = 32;
static constexpr int NSTEP = KP / BK;   // 25
static constexpr int AELEM = 8192;      // A-fp32 region, u16 units (16 KB)
static constexpr int BUFE  = 18432;     // per-buffer u16 units (A 16KB + B 20KB)
static constexpr int H1STR = 328;

__device__ __forceinline__ u16 f2bf(float f) {
  unsigned u = __builtin_bit_cast(unsigned, f);
  u += 0x7fffu + ((u >> 16) & 1u);   // RNE
  return (u16)(u >> 16);
}

__device__ __forceinline__ void gll16(const void* g, void* l) {
  __builtin_amdgcn_global_load_lds(
      (const __attribute__((address_space(1))) void*)g,
      (__attribute__((address_space(3))) void*)l, 16, 0, 0);
}

// ---- Kernel A: fold conv into first linear layer; weff_t[n][k] bf16, zero-padded ----
__global__ void build_weff(const float* __restrict__ cw,
                           const float* __restrict__ w1,
                           u16* __restrict__ weff) {
  int idx = blockIdx.x * 256 + threadIdx.x;
  if (idx >= NP * KP) return;
  int n = idx / KP;
  int k = idx - n * KP;
  float acc = 0.f;
  if (n < NDIM && k < KDIM) {
    int r = k / 28, c = k - (k / 28) * 28;
    #pragma unroll
    for (int dr = 0; dr < 3; ++dr) {
      int orr = r - dr;
      if ((unsigned)orr < 26u) {
        #pragma unroll
        for (int dc = 0; dc < 3; ++dc) {
          int oc = c - dc;
          if ((unsigned)oc < 26u)
            acc += cw[dr * 3 + dc] * w1[(orr * 26 + oc) * NDIM + n];
        }
      }
    }
  }
  weff[n * KP + k] = f2bf(acc);
}

// ---- Kernel B: out = relu(x @ Weff + b1) @ w2 + b2 ----
// 512 threads, 8 waves (2m x 4n). Both tiles staged via global_load_lds into
// chunk-major LDS (bank-conflict-free fragment reads), double-buffered,
// one barrier per K-step. A staged as fp32, converted at fragment read.
__global__ void __launch_bounds__(512, 4)
fused_mlp(const float* __restrict__ x, const float* __restrict__ b1,
          const float* __restrict__ w2, const float* __restrict__ b2,
          const u16* __restrict__ weff, float* __restrict__ out) {
  // Per buffer: A-fp32 chunk-major [q=0..7][r=0..127] 16B chunks (16 KB),
  //             B-bf16 chunk-major [q=0..3][r=0..319] 16B chunks (20 KB).
  // Epilogue overlay: H1[64][328] (41984 B) + W2T[16][328] (10496 B) = 52480 B.
  __shared__ __align__(16) u16 lds[2 * BUFE];   // 73728 B -> 2 blocks/CU

  const int tid  = threadIdx.x;
  const int wv   = tid >> 6;
  const int lane = tid & 63;
  const int l16  = lane & 15;
  const int lhi  = lane >> 4;       // 0..3
  const int wn   = wv & 3;          // n-group: cols wn*80..+80
  const int wm   = wv >> 2;         // m-half:  rows wm*64..+64
  const int bm   = blockIdx.x * BM;

  // --- B staging chunk ids (c = q*320 + r), 1280 chunks over 512 threads ---
  int rB[3], qB[3];
  #pragma unroll
  for (int it = 0; it < 3; ++it) {
    int c = tid + it * 512;
    int q = (c >= 320) + (c >= 640) + (c >= 960);
    qB[it] = q;
    rB[it] = c - q * 320;
  }
  // --- A staging chunk ids (c = q*128 + r), 1024 chunks over 512 threads ---
  const int qA0 = tid >> 7, rA0 = tid & 127;          // it=0: q 0..3 (k0..k0+15)
  const int qA1 = (tid + 512) >> 7, rA1 = tid & 127;  // it=1: q 4..7 (k0+16..k0+31)

  f32x4 acc[4][5];
  #pragma unroll
  for (int mi = 0; mi < 4; ++mi)
    #pragma unroll
    for (int ni = 0; ni < 5; ++ni)
      acc[mi][ni] = (f32x4){0.f, 0.f, 0.f, 0.f};

  auto stageA = [&](int nxt, int k0) {
    gll16(x + (size_t)(bm + rA0) * KDIM + k0 + qA0 * 4,
          (char*)(lds + nxt * BUFE) + tid * 16);
    if (k0 + 16 < KDIM) {   // last step: k 784..799 stays stale; B zero-pad kills it
      gll16(x + (size_t)(bm + rA1) * KDIM + k0 + qA1 * 4,
            (char*)(lds + nxt * BUFE) + (tid + 512) * 16);
    }
  };
  auto stageB = [&](int nxt, int k0) {
    char* base = (char*)(lds + nxt * BUFE + AELEM);
    gll16(weff + (size_t)rB[0] * KP + k0 + qB[0] * 8, base + tid * 16);
    gll16(weff + (size_t)rB[1] * KP + k0 + qB[1] * 8, base + (tid + 512) * 16);
    if (tid < 256)
      gll16(weff + (size_t)rB[2] * KP + k0 + qB[2] * 8, base + (tid + 1024) * 16);
  };

  // fragment read offsets (u16 units)
  const int aoff = lhi * 2048 + (wm * 64 + l16) * 8;  // + mi*128; k-hi half +1024
  const int boff = lhi * 2560 + (wn * 80 + l16) * 8;  // + ni*128

  stageA(0, 0);
  stageB(0, 0);
  __syncthreads();

  int cur = 0;
  for (int t = 0; t < NSTEP; ++t) {
    if (t + 1 < NSTEP) {          // issue next tile early; lands before the barrier
      stageA(cur ^ 1, (t + 1) * BK);
      stageB(cur ^ 1, (t + 1) * BK);
    }
    const u16* Ab = lds + cur * BUFE;
    const u16* Bb = Ab + AELEM;
    bf16x8 bfr[5];
    #pragma unroll
    for (int ni = 0; ni < 5; ++ni)
      bfr[ni] = *reinterpret_cast<const bf16x8*>(Bb + boff + ni * 128);
    #pragma unroll
    for (int mi = 0; mi < 4; ++mi) {
      f32x4 a0 = *reinterpret_cast<const f32x4*>(Ab + aoff + mi * 128);
      f32x4 a1 = *reinterpret_cast<const f32x4*>(Ab + aoff + mi * 128 + 1024);
      bf16x8 am;
      #pragma unroll
      for (int j = 0; j < 4; ++j) {
        am[j]     = (short)f2bf(a0[j]);
        am[4 + j] = (short)f2bf(a1[j]);
      }
      #pragma unroll
      for (int ni = 0; ni < 5; ++ni)
        acc[mi][ni] = __builtin_amdgcn_mfma_f32_16x16x32_bf16(am, bfr[ni], acc[mi][ni], 0, 0, 0);
    }
    __syncthreads();
    cur ^= 1;
  }

  // ---- epilogue: h1 = relu(acc + b1); out = h1 @ w2 + b2 ----
  u16* H1  = lds;                 // [64][328]
  u16* W2T = lds + 64 * H1STR;    // [16][328], ends at 26240 <= 36864

  for (int i = tid; i < 16 * NP; i += 512) {
    int d = i / NP, n = i - d * NP;
    float v = (d < DDIM && n < NDIM) ? w2[n * DDIM + d] : 0.f;
    W2T[d * H1STR + n] = f2bf(v);
  }
  float biasv[5];
  #pragma unroll
  for (int ni = 0; ni < 5; ++ni) {
    int col = wn * 80 + ni * 16 + l16;
    biasv[ni] = (col < NDIM) ? b1[col] : 0.f;
  }

  #pragma unroll
  for (int p = 0; p < 2; ++p) {
    if (wm == p) {
      #pragma unroll
      for (int mi = 0; mi < 4; ++mi) {
        #pragma unroll
        for (int ni = 0; ni < 5; ++ni) {
          int col = wn * 80 + ni * 16 + l16;
          int rb  = mi * 16 + lhi * 4;
          #pragma unroll
          for (int r = 0; r < 4; ++r) {
            float h = acc[mi][ni][r] + biasv[ni];
            H1[(rb + r) * H1STR + col] = f2bf(fmaxf(h, 0.f));
          }
        }
      }
    }
    __syncthreads();               // H1 (and W2T on p==0) visible
    if (wv < 4) {
      f32x4 a2c = (f32x4){0.f, 0.f, 0.f, 0.f};
      #pragma unroll
      for (int ks = 0; ks < NP / 32; ++ks) {
        bf16x8 a2 = *reinterpret_cast<const bf16x8*>(H1 + (wv * 16 + l16) * H1STR + ks * 32 + lhi * 8);
        bf16x8 bw = *reinterpret_cast<const bf16x8*>(W2T + l16 * H1STR + ks * 32 + lhi * 8);
        a2c = __builtin_amdgcn_mfma_f32_16x16x32_bf16(a2, bw, a2c, 0, 0, 0);
      }
      if (l16 < DDIM) {
        float bb = b2[l16];
        #pragma unroll
        for (int r = 0; r < 4; ++r) {
          int row = bm + p * 64 + wv * 16 + lhi * 4 + r;
          out[(size_t)row * DDIM + l16] = a2c[r] + bb;
        }
      }
    }
    __syncthreads();               // before next pass overwrites H1
  }
}

extern "C" void kernel_launch(void* const* d_in, const int* in_sizes, int n_in,
                              void* d_out, int out_size, void* d_ws, size_t ws_size,
                              hipStream_t stream) {
  const float* x  = (const float*)d_in[0];
  const float* cw = (const float*)d_in[1];
  const float* w1 = (const float*)d_in[2];
  const float* b1 = (const float*)d_in[3];
  const float* w2 = (const float*)d_in[4];
  const float* b2 = (const float*)d_in[5];
  float* out = (float*)d_out;
  u16* weff = (u16*)d_ws;   // 320*800*2 = 512000 bytes

  hipLaunchKernelGGL(build_weff, dim3((NP * KP + 255) / 256), dim3(256), 0, stream,
                     cw, w1, weff);
  hipLaunchKernelGGL(fused_mlp, dim3(65536 / BM), dim3(512), 0, stream,
                     x, b1, w2, b2, weff, out);
}